// Round 10
// baseline (824.137 us; speedup 1.0000x reference)
//
#include <hip/hip_runtime.h>
#include <hip/hip_bf16.h>
#include <math.h>

typedef __hip_bfloat16 bf16;

// Problem constants
constexpr int cB = 16, cL = 2048, cWIN = 128, cD = 512, cH = 8, cFF = 2048;
constexpr int cNL = 3, cV = 32000, cM = 32;
constexpr int cHD = cD / cH;     // 64
constexpr int cS = cWIN + 1;     // 129
constexpr float cEPS = 1e-5f;
constexpr float cRECON_W = 0.1f;
constexpr int cNVT = cV / 128;   // 250 vocab tiles

__device__ __forceinline__ float b2f(bf16 x) { return __bfloat162float(x); }

// dtype-agnostic load with ELEMENT offset: f32 flag selects interpretation.
__device__ __forceinline__ float ldx(const void* p, size_t i, int f32) {
    return f32 ? ((const float*)p)[i]
               : __bfloat162float(((const bf16*)p)[i]);
}

// f32 -> bf16 bits, round-to-nearest-even
__device__ __forceinline__ unsigned int f2bf(float f) {
    union { float f; unsigned int u; } v; v.f = f;
    unsigned int u = v.u + 0x7FFFu + ((v.u >> 16) & 1u);
    return u >> 16;
}

// async global->LDS 16B per lane (dest = wave-uniform base + lane*16)
__device__ __forceinline__ void glds16(const unsigned short* g, unsigned short* l) {
    __builtin_amdgcn_global_load_lds(
        (const __attribute__((address_space(1))) void*)g,
        (__attribute__((address_space(3))) void*)l, 16, 0, 0);
}

// MFMA fragment types
typedef short bf16x8 __attribute__((ext_vector_type(8)));
typedef float f32x4  __attribute__((ext_vector_type(4)));

// ---------------------------------------------------------------------------
__global__ void detect_kernel(const void* __restrict__ x0raw, int* __restrict__ flag)
{
    const unsigned short* h = (const unsigned short*)x0raw;
    int tid = threadIdx.x;
    int cnt = 0;
    for (int j = tid; j < 8192; j += 256) {
        unsigned short u = h[2 * j];
        int e = (u >> 7) & 0xFF;
        if (e >= 134) cnt++;
    }
    __shared__ int red[256];
    red[tid] = cnt; __syncthreads();
    for (int off = 128; off > 0; off >>= 1) {
        if (tid < off) red[tid] += red[tid + off];
        __syncthreads();
    }
    if (tid == 0) *flag = (red[0] > 400) ? 1 : 0;
}

// ---------------------------------------------------------------------------
// 16 chunks (256 blocks) for occupancy; 128 tokens each.
__global__ __launch_bounds__(512) void pools_part_kernel(
    const int* __restrict__ tok, const int* __restrict__ wstart,
    const int* __restrict__ wend, const void* __restrict__ emb,
    float* __restrict__ part, const int* __restrict__ dflag)
{
    const int f32 = *dflag;
    int chunk = blockIdx.x;          // 0..15
    int b = blockIdx.y;              // 0..15
    int d = threadIdx.x;             // 0..511
    int ws_ = wstart[b], we_ = wend[b];
    float sl = 0.f, sr = 0.f, sg = 0.f;
    int l0 = chunk * 128;
    for (int l = l0; l < l0 + 128; ++l) {
        int t = tok[b * cL + l];
        float h = ldx(emb, (size_t)t * cD + d, f32);
        sg += h;
        if (l < ws_) sl += h;
        if (l >= we_) sr += h;
    }
    size_t base = ((size_t)(b * 16 + chunk)) * 3 * cD;
    part[base + d]            = sl;
    part[base + cD + d]       = sr;
    part[base + 2 * cD + d]   = sg;
}

// combine partials + FUSED time-embedding + FUSED labels (labels live in a
// DEDICATED workspace slot never aliased by GEMM buffers).
__global__ __launch_bounds__(512) void pools_combine_kernel(
    const float* __restrict__ part, const int* __restrict__ mids,
    const int* __restrict__ mlen, const int* __restrict__ wstart,
    const int* __restrict__ wend, const void* __restrict__ emb,
    unsigned short* __restrict__ featb, const void* __restrict__ t_arr,
    unsigned short* __restrict__ tfbb, const int* __restrict__ tok,
    int* __restrict__ labels, const int* __restrict__ dflag)
{
    const int f32 = *dflag;
    int b = blockIdx.x;
    int d = threadIdx.x;
    int ws_ = wstart[b], we_ = wend[b];
    float sl = 0.f, sr = 0.f, sg = 0.f;
    for (int c = 0; c < 16; ++c) {
        size_t base = ((size_t)(b * 16 + c)) * 3 * cD;
        sl += part[base + d];
        sr += part[base + cD + d];
        sg += part[base + 2 * cD + d];
    }
    int ml = mlen[b];
    float sm = 0.f;
    for (int j = 0; j < cM; ++j) {
        if (j < ml) sm += ldx(emb, (size_t)mids[b * cM + j] * cD + d, f32);
    }
    unsigned short* fr = featb + (size_t)b * (4 * cD);
    fr[d]            = (unsigned short)f2bf(sm / fmaxf((float)ml, 1.f));
    fr[cD + d]       = (unsigned short)f2bf(sl / fmaxf((float)ws_, 1.f));
    fr[2 * cD + d]   = (unsigned short)f2bf(sr / fmaxf((float)(cL - we_), 1.f));
    fr[3 * cD + d]   = (unsigned short)f2bf(sg / (float)cL);

    // fused tf: time-frequency embedding row b
    {
        float t = ldx(t_arr, b, f32);
        const int half = cD / 2;
        float v;
        if (d < half) {
            float frq = expf(-logf(10000.f) * (float)d / (float)(half - 1));
            v = sinf(t * frq);
        } else {
            float frq = expf(-logf(10000.f) * (float)(d - half) / (float)(half - 1));
            v = cosf(t * frq);
        }
        tfbb[(size_t)b * cD + d] = (unsigned short)f2bf(v);
    }

    // fused labels: rows b*128 .. b*128+127 (dedicated buffer)
    if (d < cWIN) {
        int actual = min(max(we_ - ws_, 0), cWIN);
        labels[b * cWIN + d] =
            (d < actual) ? tok[b * cL + min(ws_ + d, cL - 1)] : -1;
    }
}

// ---------------------------------------------------------------------------
__global__ __launch_bounds__(512) void build_x_kernel(
    const int* __restrict__ tok, const int* __restrict__ wstart,
    const int* __restrict__ wend, const void* __restrict__ t_arr,
    const void* __restrict__ x0, const void* __restrict__ emb,
    const float* __restrict__ cond, const float* __restrict__ temb,
    float* __restrict__ x, unsigned short* __restrict__ xbf,
    float* __restrict__ x1, float* __restrict__ xt,
    const int* __restrict__ dflag)
{
    const int f32 = *dflag;
    int row = blockIdx.x;
    int b = row / cS, s = row % cS;
    int d = threadIdx.x;
    if (s == 0) {
        float cv = cond[b * cD + d];
        x[(size_t)row * cD + d] = cv;
        xbf[(size_t)row * cD + d] = (unsigned short)f2bf(cv);
        return;
    }
    int i = s - 1;
    int ws_ = wstart[b], we_ = wend[b];
    int actual = min(max(we_ - ws_, 0), cWIN);
    int idx = min(ws_ + i, cL - 1);
    float x1v = 0.f;
    if (i < actual) x1v = ldx(emb, (size_t)tok[b * cL + idx] * cD + d, f32);
    float t = ldx(t_arr, b, f32);
    float x0v = ldx(x0, ((size_t)b * cWIN + i) * cD + d, f32);
    float xtv = (1.f - t) * x0v + t * x1v;
    size_t ro = ((size_t)b * cWIN + i) * cD + d;
    x1[ro] = x1v;
    xt[ro] = xtv;
    float xv = xtv + temb[b * cD + d];
    x[(size_t)row * cD + d] = xv;
    xbf[(size_t)row * cD + d] = (unsigned short)f2bf(xv);
}

// ---------------------------------------------------------------------------
// R14 GEMM (proven): 512 threads / 8 waves per 64x64 tile. Each wave owns a
// 16x32 output sub-tile. BK=64, double-buffered LDS, PREFETCH-2, involutive
// slot-XOR on LDS write+read. amap=1: A rows remapped (skip cond rows).
constexpr int GL2 = 72;   // LDS row stride in shorts (144 B)
__global__ __launch_bounds__(512) void gemm_bf(
    const unsigned short* __restrict__ Abf, const void* __restrict__ Wb,
    size_t wOff, const void* __restrict__ biasb, size_t bOff,
    float* __restrict__ Cf, unsigned short* __restrict__ Cbf,
    int Mdim, int Ndim, int Kdim, int relu, int obf, int amap,
    const int* __restrict__ dflag)
{
    const int f32 = *dflag;
    const float* Wf = (const float*)Wb + wOff;
    const unsigned short* Wh = (const unsigned short*)Wb + wOff;
    __shared__ unsigned short As[2][64 * GL2];
    __shared__ unsigned short Bs[2][64 * GL2];
    const int tid = threadIdx.x;
    const int lane = tid & 63;
    const int wid = tid >> 6;          // 0..7
    const int wm = wid >> 1;           // 0..3: 16-row band
    const int wn = wid & 1;            // 0..1: 32-col band
    const int quad = lane >> 4, lm = lane & 15;
    const int m0 = blockIdx.y * 64;
    const int n0 = blockIdx.x * 64;

    f32x4 acc0 = (f32x4){0.f, 0.f, 0.f, 0.f};
    f32x4 acc1 = (f32x4){0.f, 0.f, 0.f, 0.f};

    const int srow = tid >> 3;                       // 0..63
    const int sc8  = (tid & 7) * 8;                  // global short offset
    const int ssw  = ((tid & 7) ^ ((tid >> 3) & 7)) * 8;  // swizzled LDS slot
    const int lmm  = lm & 7;                         // read-side row&7

    auto loadA = [&](int k0, uint4& r) {
        int r0 = m0 + srow;
        uint4 v = {0u, 0u, 0u, 0u};
        if (r0 < Mdim) {
            size_t ar = amap ? ((size_t)(r0 >> 7) * cS + 1 + (r0 & 127))
                             : (size_t)r0;
            v = *(const uint4*)(Abf + ar * Kdim + k0 + sc8);
        }
        r = v;
    };
    auto loadB = [&](int k0, uint4& r) {
        size_t g = (size_t)(n0 + srow) * Kdim + k0 + sc8;
        if (f32) {
            float4 v0 = *(const float4*)(Wf + g);
            float4 v1 = *(const float4*)(Wf + g + 4);
            r = make_uint4(
                f2bf(v0.x) | (f2bf(v0.y) << 16), f2bf(v0.z) | (f2bf(v0.w) << 16),
                f2bf(v1.x) | (f2bf(v1.y) << 16), f2bf(v1.z) | (f2bf(v1.w) << 16));
        } else {
            r = *(const uint4*)(Wh + g);
        }
    };
    auto stores = [&](int buf, const uint4& ra, const uint4& rb) {
        *(uint4*)(&As[buf][srow * GL2 + ssw]) = ra;
        *(uint4*)(&Bs[buf][srow * GL2 + ssw]) = rb;
    };
    auto compute = [&](int buf) {
        #pragma unroll
        for (int kk = 0; kk < 2; ++kk) {
            const int sl = ((kk * 4 + quad) ^ lmm) * 8;
            bf16x8 a0 = *(const bf16x8*)(&As[buf][(wm * 16 + lm) * GL2 + sl]);
            bf16x8 b0 = *(const bf16x8*)(&Bs[buf][(wn * 32 + lm) * GL2 + sl]);
            bf16x8 b1 = *(const bf16x8*)(&Bs[buf][(wn * 32 + 16 + lm) * GL2 + sl]);
            acc0 = __builtin_amdgcn_mfma_f32_16x16x32_bf16(a0, b0, acc0, 0, 0, 0);
            acc1 = __builtin_amdgcn_mfma_f32_16x16x32_bf16(a0, b1, acc1, 0, 0, 0);
        }
    };

    uint4 raA, rbA, raB, rbB;
    loadA(0, raA);  loadB(0, rbA);
    loadA(64, raB); loadB(64, rbB);
    const int nk = Kdim >> 6;          // even for all call sites
    for (int t = 0; t < nk; t += 2) {
        stores(0, raA, rbA);
        __syncthreads();
        if (t + 2 < nk) { loadA((t + 2) * 64, raA); loadB((t + 2) * 64, rbA); }
        compute(0);
        stores(1, raB, rbB);
        __syncthreads();
        if (t + 3 < nk) { loadA((t + 3) * 64, raB); loadB((t + 3) * 64, rbB); }
        compute(1);
    }

    #pragma unroll
    for (int in = 0; in < 2; ++in) {
        int gc = n0 + wn * 32 + in * 16 + lm;
        float bv = ldx(biasb, bOff + gc, f32);
        const f32x4& a = in ? acc1 : acc0;
        #pragma unroll
        for (int r = 0; r < 4; ++r) {
            int gr = m0 + wm * 16 + quad * 4 + r;
            if (gr < Mdim) {
                float v = a[r] + bv;
                if (relu) v = fmaxf(v, 0.f);
                if (obf) Cbf[(size_t)gr * Ndim + gc] = (unsigned short)f2bf(v);
                else     Cf[(size_t)gr * Ndim + gc] = v;
            }
        }
    }
}

// ---------------------------------------------------------------------------
// MFMA flash-style attention, bf16 I/O, z-split grid: grid (H, B, 3);
// wave wid<3 of block z owns query tile t = z*3 + wid (9 tiles total).
__global__ __launch_bounds__(256) void attn_mfma_kernel(
    const unsigned short* __restrict__ qkv, unsigned short* __restrict__ ctx)
{
    constexpr int SP = 160;        // padded S (10 * 16)
    constexpr int KP = 72;         // Ks row stride in shorts
    constexpr int VP = 168;        // Vt / P row stride in shorts
    const int h = blockIdx.x, b = blockIdx.y, z = blockIdx.z;
    const int tid = threadIdx.x;
    const int lane = tid & 63;
    const int wid = tid >> 6;
    const int quad = lane >> 4, lm = lane & 15;

    __shared__ unsigned short Ks[SP * KP];       // [key][64]
    __shared__ unsigned short Vt[64 * VP];       // [d][key]
    __shared__ unsigned short Pl[4 * 16 * VP];   // per-wave [qrow][key]

    const unsigned short* base = qkv + (size_t)b * cS * (3 * cD) + h * cHD;

    // Stage K row-major (uint4 = 8 bf16 per chunk)
    for (int c = tid; c < SP * 8; c += 256) {
        int row = c >> 3, g = c & 7;
        uint4 v = {0u, 0u, 0u, 0u};
        if (row < cS)
            v = *(const uint4*)(base + (size_t)row * (3 * cD) + cD + g * 8);
        *(uint4*)(Ks + row * KP + g * 8) = v;
    }
    // Stage V transposed (uint2 = 4 bf16, scattered per-d rows)
    for (int c = tid; c < SP * 16; c += 256) {
        int key = c >> 4, d4 = c & 15;
        uint2 v = {0u, 0u};
        if (key < cS)
            v = *(const uint2*)(base + (size_t)key * (3 * cD) + 2 * cD + d4 * 4);
        Vt[(d4 * 4 + 0) * VP + key] = (unsigned short)(v.x & 0xFFFFu);
        Vt[(d4 * 4 + 1) * VP + key] = (unsigned short)(v.x >> 16);
        Vt[(d4 * 4 + 2) * VP + key] = (unsigned short)(v.y & 0xFFFFu);
        Vt[(d4 * 4 + 3) * VP + key] = (unsigned short)(v.y >> 16);
    }
    __syncthreads();

    unsigned short* Pw = Pl + wid * (16 * VP);
    const int t = z * 3 + wid;        // 9 tiles, wid==3 idles after staging

    if (wid < 3 && t < 9) {
        int qs = t * 16 + lm;
        bf16x8 aq[2];
        #pragma unroll
        for (int j = 0; j < 8; ++j) { aq[0][j] = 0; aq[1][j] = 0; }
        if (qs < cS) {
            const unsigned short* qrow = base + (size_t)qs * (3 * cD);
            aq[0] = *(const bf16x8*)(qrow + quad * 8);
            aq[1] = *(const bf16x8*)(qrow + 32 + quad * 8);
        }

        // scores: sc[n][r] = S[q = t*16 + quad*4 + r][key = n*16 + lm]
        f32x4 sc[10];
        #pragma unroll
        for (int n = 0; n < 10; ++n) {
            sc[n] = (f32x4){0.f, 0.f, 0.f, 0.f};
            bf16x8 bk0 = *(const bf16x8*)(Ks + (n * 16 + lm) * KP + quad * 8);
            sc[n] = __builtin_amdgcn_mfma_f32_16x16x32_bf16(aq[0], bk0, sc[n], 0, 0, 0);
            bf16x8 bk1 = *(const bf16x8*)(Ks + (n * 16 + lm) * KP + 32 + quad * 8);
            sc[n] = __builtin_amdgcn_mfma_f32_16x16x32_bf16(aq[1], bk1, sc[n], 0, 0, 0);
        }

        // softmax per accumulator row; key-dim lives across the 16 lm lanes
        #pragma unroll
        for (int r = 0; r < 4; ++r) {
            float mx = -3.0e38f;
            #pragma unroll
            for (int n = 0; n < 10; ++n) {
                float v = sc[n][r] * 0.125f;
                mx = fmaxf(mx, ((n * 16 + lm) < cS) ? v : -3.0e38f);
            }
            #pragma unroll
            for (int msk = 1; msk < 16; msk <<= 1)
                mx = fmaxf(mx, __shfl_xor(mx, msk));
            float p[10];
            float sum = 0.f;
            #pragma unroll
            for (int n = 0; n < 10; ++n) {
                float e = ((n * 16 + lm) < cS) ? expf(sc[n][r] * 0.125f - mx) : 0.f;
                p[n] = e; sum += e;
            }
            #pragma unroll
            for (int msk = 1; msk < 16; msk <<= 1)
                sum += __shfl_xor(sum, msk);
            float inv = 1.f / sum;
            unsigned short* pr = Pw + (quad * 4 + r) * VP + lm;
            #pragma unroll
            for (int n = 0; n < 10; ++n)
                pr[n * 16] = (unsigned short)f2bf(p[n] * inv);
        }

        // per-wave LDS visibility for P; sched_barrier per guide rule 18
        asm volatile("s_waitcnt lgkmcnt(0)" ::: "memory");
        __builtin_amdgcn_sched_barrier(0);

        // PV: O[16][64] = P[16][160] @ V[160][64]
        f32x4 o[4];
        #pragma unroll
        for (int j = 0; j < 4; ++j) o[j] = (f32x4){0.f, 0.f, 0.f, 0.f};
        #pragma unroll
        for (int ks = 0; ks < 5; ++ks) {
            bf16x8 ap = *(const bf16x8*)(Pw + lm * VP + ks * 32 + quad * 8);
            #pragma unroll
            for (int j = 0; j < 4; ++j) {
                bf16x8 bv = *(const bf16x8*)(Vt + (j * 16 + lm) * VP + ks * 32 + quad * 8);
                o[j] = __builtin_amdgcn_mfma_f32_16x16x32_bf16(ap, bv, o[j], 0, 0, 0);
            }
        }

        #pragma unroll
        for (int r = 0; r < 4; ++r) {
            int s_ = t * 16 + quad * 4 + r;
            if (s_ < cS) {
                unsigned short* orow = ctx + ((size_t)(b * cS + s_)) * cD + h * cHD;
                #pragma unroll
                for (int j = 0; j < 4; ++j)
                    orow[j * 16 + lm] = (unsigned short)f2bf(o[j][r]);
            }
        }
    }
}

// ---------------------------------------------------------------------------
__global__ __launch_bounds__(256) void resid_ln_kernel(
    float* __restrict__ x, const float* __restrict__ h,
    const void* __restrict__ g, const void* __restrict__ bta, size_t off,
    unsigned short* __restrict__ xbf, const int* __restrict__ dflag)
{
    const int f32 = *dflag;
    int row = blockIdx.x;
    int tid = threadIdx.x;
    __shared__ float red[256];
    float v[2];
    float s = 0.f;
    #pragma unroll
    for (int j = 0; j < 2; ++j) {
        int d = tid + j * 256;
        v[j] = x[(size_t)row * cD + d] + h[(size_t)row * cD + d];
        s += v[j];
    }
    red[tid] = s; __syncthreads();
    for (int o = 128; o > 0; o >>= 1) {
        if (tid < o) red[tid] += red[tid + o];
        __syncthreads();
    }
    float mean = red[0] / (float)cD;
    __syncthreads();
    float vs = 0.f;
    #pragma unroll
    for (int j = 0; j < 2; ++j) { float dd = v[j] - mean; vs += dd * dd; }
    red[tid] = vs; __syncthreads();
    for (int o = 128; o > 0; o >>= 1) {
        if (tid < o) red[tid] += red[tid + o];
        __syncthreads();
    }
    float rs = rsqrtf(red[0] / (float)cD + cEPS);
    #pragma unroll
    for (int j = 0; j < 2; ++j) {
        int d = tid + j * 256;
        float ov = (v[j] - mean) * rs * ldx(g, off + d, f32) + ldx(bta, off + d, f32);
        x[(size_t)row * cD + d] = ov;
        xbf[(size_t)row * cD + d] = (unsigned short)f2bf(ov);
    }
}

// ---------------------------------------------------------------------------
// Fused predx1 + vel: one pass over pv; writes bf16 pred_x1 and the
// per-row velocity partial.
__global__ __launch_bounds__(512) void predvel_kernel(
    const float* __restrict__ xt, const float* __restrict__ pv,
    const float* __restrict__ x1, const void* __restrict__ x0,
    const void* __restrict__ t_arr, const int* __restrict__ wstart,
    const int* __restrict__ wend, unsigned short* __restrict__ px1,
    float* __restrict__ velpart, const int* __restrict__ dflag)
{
    const int f32 = *dflag;
    int row = blockIdx.x;
    int b = row >> 7, i = row & 127;
    int d = threadIdx.x;
    float t = ldx(t_arr, b, f32);
    size_t o = (size_t)row * cD + d;
    float pvv = pv[o];
    px1[o] = (unsigned short)f2bf(xt[o] + (1.f - t) * pvv);
    int actual = min(max(wend[b] - wstart[b], 0), cWIN);
    float s = 0.f;
    if (i < actual) {
        float tv = x1[o] - ldx(x0, o, f32);
        float diff = pvv - tv;
        s = diff * diff;
    }
    __shared__ float red[512];
    red[d] = s; __syncthreads();
    for (int off = 256; off > 0; off >>= 1) {
        if (d < off) red[d] += red[d + off];
        __syncthreads();
    }
    if (d == 0) velpart[row] = red[0];
}

// ---------------------------------------------------------------------------
// pre-convert decode_W -> bf16 (only needed when input is f32)
__global__ __launch_bounds__(256) void cvt_w_kernel(
    const void* __restrict__ Wsrc, unsigned short* __restrict__ dst,
    const int* __restrict__ dflag)
{
    if (!*dflag) return;   // bf16 input: decode reads source directly
    const float4* src = (const float4*)Wsrc;
    size_t n4 = (size_t)cV * cD / 4;
    for (size_t i = (size_t)blockIdx.x * 256 + threadIdx.x; i < n4;
         i += (size_t)gridDim.x * 256) {
        float4 v = src[i];
        unsigned int p0 = f2bf(v.x) | (f2bf(v.y) << 16);
        unsigned int p1 = f2bf(v.z) | (f2bf(v.w) << 16);
        ((uint2*)dst)[i] = make_uint2(p0, p1);
    }
}

// ---------------------------------------------------------------------------
// R18 FAST decode: R12 geometry (256 thr, [128][32] tiles, involutive swizzle)
// + 2-deep DOUBLE-BUFFERED glds16 pipeline with COUNTED vmcnt and raw
// s_barrier (T4): never drain vmcnt to 0 in the main loop. Per step:
//   vmcnt(4)  -> current tile's 4 glds16 landed (next tile stays in flight)
//   s_barrier -> all waves' tiles visible
//   compute   -> 8 ds_read_b128 + 16 MFMA
//   lgkmcnt(0) + sched_barrier(0) + s_barrier -> reads done, safe to overwrite
//   issue stage(t+2) into the just-freed buffer
// Tail: vmcnt(0) only at t=15. Epilogue aliases the (dead) staging LDS.
__global__ __launch_bounds__(256) void decode_mfma2_kernel(
    const unsigned short* __restrict__ hbf, const unsigned short* __restrict__ wbf,
    const void* __restrict__ dW, const void* __restrict__ db,
    const int* __restrict__ labels,
    float* __restrict__ pm, float* __restrict__ ps, float* __restrict__ lab,
    const int* __restrict__ dflag)
{
    const int f32 = *dflag;
    const unsigned short* Wsrc = f32 ? wbf : (const unsigned short*)dW;
    const int bid = blockIdx.x;
    const int xcd = bid & 7;
    const int local = bid >> 3;            // 0..511
    const int nt = xcd * 32 + (local >> 4);
    const int mt = local & 15;
    if (nt >= cNVT) return;                // uniform exit, no barriers crossed
    const int m0 = mt * 128, n0 = nt * 128;

    __shared__ __align__(16) char smem[32768];   // 2 x (A 8KB + B 8KB); epilogue aliases
    unsigned short* As0 = (unsigned short*)smem;  // [128][32]
    unsigned short* Bs0 = As0 + 4096;
    unsigned short* As1 = Bs0 + 4096;
    unsigned short* Bs1 = As1 + 4096;

    const int tid = threadIdx.x;
    const int lane = tid & 63;
    const int wid = tid >> 6;
    const int wm = wid >> 1, wn = wid & 1;
    const int quad = lane >> 4, lm = lane & 15;

    // staging geometry: each glds16 covers 16 rows (64 lanes x 16 B = 1 KB)
    const int grow  = lane >> 2;                       // row within chunk
    const int gslot = (lane & 3) ^ ((lane >> 3) & 3);  // swizzled global slot
    const int rslot = (quad ^ ((lm >> 1) & 3)) * 8;    // read-side slot (shorts)

    // per-wave global bases (rows wid*32 .. wid*32+31 over two chunks)
    const unsigned short* gA = hbf  + (size_t)(m0 + wid * 32 + grow) * cD + gslot * 8;
    const unsigned short* gB = Wsrc + (size_t)(n0 + wid * 32 + grow) * cD + gslot * 8;

    f32x4 acc[4][4];
    #pragma unroll
    for (int i = 0; i < 4; ++i)
        #pragma unroll
        for (int j = 0; j < 4; ++j)
            acc[i][j] = (f32x4){0.f, 0.f, 0.f, 0.f};

    auto stage = [&](int k0, unsigned short* A_, unsigned short* B_) {
        #pragma unroll
        for (int c = 0; c < 2; ++c) {
            glds16(gA + (size_t)c * 16 * cD + k0, A_ + (wid * 2 + c) * 512);
            glds16(gB + (size_t)c * 16 * cD + k0, B_ + (wid * 2 + c) * 512);
        }
    };
    auto compute = [&](const unsigned short* A_, const unsigned short* B_) {
        bf16x8 af[4], bfr[4];
        #pragma unroll
        for (int im = 0; im < 4; ++im)
            af[im] = *(const bf16x8*)(A_ + (wm * 64 + im * 16 + lm) * 32 + rslot);
        #pragma unroll
        for (int in = 0; in < 4; ++in)
            bfr[in] = *(const bf16x8*)(B_ + (wn * 64 + in * 16 + lm) * 32 + rslot);
        #pragma unroll
        for (int im = 0; im < 4; ++im)
            #pragma unroll
            for (int in = 0; in < 4; ++in)
                acc[im][in] = __builtin_amdgcn_mfma_f32_16x16x32_bf16(
                    af[im], bfr[in], acc[im][in], 0, 0, 0);
    };

    stage(0, As0, Bs0);        // 4 glds16 in flight
    stage(32, As1, Bs1);       // 8 in flight
    for (int t = 0; t < 16; ++t) {
        unsigned short* A_ = (t & 1) ? As1 : As0;
        unsigned short* B_ = (t & 1) ? Bs1 : Bs0;
        if (t < 15) asm volatile("s_waitcnt vmcnt(4)" ::: "memory");
        else        asm volatile("s_waitcnt vmcnt(0)" ::: "memory");
        __builtin_amdgcn_s_barrier();
        compute(A_, B_);
        asm volatile("s_waitcnt lgkmcnt(0)" ::: "memory");
        __builtin_amdgcn_sched_barrier(0);
        __builtin_amdgcn_s_barrier();
        if (t + 2 < 16) stage((t + 2) * 32, A_, B_);
    }

    float bv[4];
    #pragma unroll
    for (int in = 0; in < 4; ++in)
        bv[in] = ldx(db, n0 + wn * 64 + in * 16 + lm, f32);
    #pragma unroll
    for (int im = 0; im < 4; ++im)
        #pragma unroll
        for (int in = 0; in < 4; ++in)
            #pragma unroll
            for (int r = 0; r < 4; ++r)
                acc[im][in][r] += bv[in];

    #pragma unroll
    for (int im = 0; im < 4; ++im) {
        #pragma unroll
        for (int r = 0; r < 4; ++r) {
            int gr = m0 + wm * 64 + im * 16 + quad * 4 + r;
            int lb = labels[gr];
            #pragma unroll
            for (int in = 0; in < 4; ++in) {
                int col = n0 + wn * 64 + in * 16 + lm;
                if (lb == col) lab[gr] = acc[im][in][r];
            }
        }
    }

    // epilogue buffers alias the (now dead) staging LDS; the k-loop's trailing
    // barrier (t=15 second barrier) guarantees all fragment reads completed.
    float (*red)[33] = (float(*)[33])smem;               // [128][33]
    float* mrow = (float*)(smem + 16896);                // [128]
    #pragma unroll
    for (int im = 0; im < 4; ++im) {
        #pragma unroll
        for (int r = 0; r < 4; ++r) {
            int rl = wm * 64 + im * 16 + quad * 4 + r;
            float mx = acc[im][0][r];
            #pragma unroll
            for (int in = 1; in < 4; ++in) mx = fmaxf(mx, acc[im][in][r]);
            red[rl][wn * 16 + lm] = mx;
        }
    }
    __syncthreads();
    if (tid < 128) {
        float mx = red[tid][0];
        #pragma unroll
        for (int t = 1; t < 32; ++t) mx = fmaxf(mx, red[tid][t]);
        mrow[tid] = mx;
    }
    __syncthreads();
    #pragma unroll
    for (int im = 0; im < 4; ++im) {
        #pragma unroll
        for (int r = 0; r < 4; ++r) {
            int rl = wm * 64 + im * 16 + quad * 4 + r;
            float m_ = mrow[rl];
            float s = 0.f;
            #pragma unroll
            for (int in = 0; in < 4; ++in) s += expf(acc[im][in][r] - m_);
            red[rl][wn * 16 + lm] = s;
        }
    }
    __syncthreads();
    if (tid < 128) {
        float s = red[tid][0];
        #pragma unroll
        for (int t = 1; t < 32; ++t) s += red[tid][t];
        int gr = m0 + tid;
        pm[(size_t)gr * cNVT + nt] = mrow[tid];
        ps[(size_t)gr * cNVT + nt] = s;
    }
}

// ---------------------------------------------------------------------------
// FALLBACK decode: bf16 A (hbf), in-kernel W conversion, (nt, mt) grid.
constexpr int GLDS = 40;
__global__ __launch_bounds__(256) void decode_mfma_kernel(
    const unsigned short* __restrict__ hbf, const void* __restrict__ dW,
    const void* __restrict__ db, const int* __restrict__ labels,
    float* __restrict__ pm, float* __restrict__ ps, float* __restrict__ lab,
    const int* __restrict__ dflag)
{
    const int f32 = *dflag;
    const float* Wf = (const float*)dW;
    const unsigned short* Wh = (const unsigned short*)dW;
    __shared__ unsigned short As[128 * GLDS];
    __shared__ unsigned short Bs[128 * GLDS];
    const int tid = threadIdx.x;
    const int lane = tid & 63;
    const int wid = tid >> 6;
    const int wm = wid >> 1, wn = wid & 1;
    const int quad = lane >> 4, lm = lane & 15;
    const int nt = blockIdx.x;
    const int mt = blockIdx.y;
    const int m0 = mt * 128, n0 = nt * 128;

    f32x4 acc[4][4];
    #pragma unroll
    for (int i = 0; i < 4; ++i)
        #pragma unroll
        for (int j = 0; j < 4; ++j)
            acc[i][j] = (f32x4){0.f, 0.f, 0.f, 0.f};

    for (int k0 = 0; k0 < cD; k0 += 32) {
        #pragma unroll
        for (int t = 0; t < 2; ++t) {
            int idx = tid + t * 256;
            int row = idx >> 2, c = idx & 3;
            uint4 v = *(const uint4*)(hbf + (size_t)(m0 + row) * cD + k0 + c * 8);
            *(uint4*)(As + row * GLDS + c * 8) = v;
        }
        #pragma unroll
        for (int t = 0; t < 4; ++t) {
            int chunk = tid + t * 256;
            int row = chunk >> 3;
            int kc = (chunk & 7) * 4;
            size_t gro = (size_t)(n0 + row) * cD + k0 + kc;
            if (f32) {
                float4 v = *(const float4*)(Wf + gro);
                unsigned int p0 = f2bf(v.x) | (f2bf(v.y) << 16);
                unsigned int p1 = f2bf(v.z) | (f2bf(v.w) << 16);
                *(uint2*)(Bs + row * GLDS + kc) = make_uint2(p0, p1);
            } else {
                *(uint2*)(Bs + row * GLDS + kc) = *(const uint2*)(Wh + gro);
            }
        }
        __syncthreads();
        bf16x8 af[4], bfr[4];
        #pragma unroll
        for (int im = 0; im < 4; ++im) {
            int row = wm * 64 + im * 16 + lm;
            af[im] = *(const bf16x8*)(As + row * GLDS + quad * 8);
        }
        #pragma unroll
        for (int in = 0; in < 4; ++in) {
            int row = wn * 64 + in * 16 + lm;
            bfr[in] = *(const bf16x8*)(Bs + row * GLDS + quad * 8);
        }
        #pragma unroll
        for (int im = 0; im < 4; ++im)
            #pragma unroll
            for (int in = 0; in < 4; ++in)
                acc[im][in] = __builtin_amdgcn_mfma_f32_16x16x32_bf16(
                    af[im], bfr[in], acc[im][in], 0, 0, 0);
        __syncthreads();
    }

    float bv[4];
    #pragma unroll
    for (int in = 0; in < 4; ++in)
        bv[in] = ldx(db, n0 + wn * 64 + in * 16 + lm, f32);
    #pragma unroll
    for (int im = 0; im < 4; ++im)
        #pragma unroll
        for (int in = 0; in < 4; ++in)
            #pragma unroll
            for (int r = 0; r < 4; ++r)
                acc[im][in][r] += bv[in];

    #pragma unroll
    for (int im = 0; im < 4; ++im) {
        #pragma unroll
        for (int r = 0; r < 4; ++r) {
            int gr = m0 + wm * 64 + im * 16 + quad * 4 + r;
            int lb = labels[gr];
            #pragma unroll
            for (int in = 0; in < 4; ++in) {
                int col = n0 + wn * 64 + in * 16 + lm;
                if (lb == col) lab[gr] = acc[im][in][r];
            }
        }
    }

    __shared__ float red[128][33];
    __shared__ float mrow[128];
    #pragma unroll
    for (int im = 0; im < 4; ++im) {
        #pragma unroll
        for (int r = 0; r < 4; ++r) {
            int rl = wm * 64 + im * 16 + quad * 4 + r;
            float mx = acc[im][0][r];
            #pragma unroll
            for (int in = 1; in < 4; ++in) mx = fmaxf(mx, acc[im][in][r]);
            red[rl][wn * 16 + lm] = mx;
        }
    }
    __syncthreads();
    if (tid < 128) {
        float mx = red[tid][0];
        #pragma unroll
        for (int t = 1; t < 32; ++t) mx = fmaxf(mx, red[tid][t]);
        mrow[tid] = mx;
    }
    __syncthreads();
    #pragma unroll
    for (int im = 0; im < 4; ++im) {
        #pragma unroll
        for (int r = 0; r < 4; ++r) {
            int rl = wm * 64 + im * 16 + quad * 4 + r;
            float m_ = mrow[rl];
            float s = 0.f;
            #pragma unroll
            for (int in = 0; in < 4; ++in) s += expf(acc[im][in][r] - m_);
            red[rl][wn * 16 + lm] = s;
        }
    }
    __syncthreads();
    if (tid < 128) {
        float s = red[tid][0];
        #pragma unroll
        for (int t = 1; t < 32; ++t) s += red[tid][t];
        int gr = m0 + tid;
        pm[(size_t)gr * cNVT + nt] = mrow[tid];
        ps[(size_t)gr * cNVT + nt] = s;
    }
}

// ---------------------------------------------------------------------------
__global__ __launch_bounds__(64) void lse_reduce_kernel(
    const float* __restrict__ pm, const float* __restrict__ ps,
    const float* __restrict__ lab, const int* __restrict__ labels,
    float* __restrict__ logppart)
{
    int r = blockIdx.x;
    int tid = threadIdx.x;
    if (labels[r] < 0) {
        if (tid == 0) logppart[r] = 0.f;
        return;
    }
    float m = -1e30f;
    for (int c = tid; c < cNVT; c += 64) m = fmaxf(m, pm[(size_t)r * cNVT + c]);
    for (int off = 32; off > 0; off >>= 1) m = fmaxf(m, __shfl_down(m, off));
    m = __shfl(m, 0);
    float s = 0.f;
    for (int c = tid; c < cNVT; c += 64)
        s += ps[(size_t)r * cNVT + c] * expf(pm[(size_t)r * cNVT + c] - m);
    for (int off = 32; off > 0; off >>= 1) s += __shfl_down(s, off);
    if (tid == 0) logppart[r] = lab[r] - (m + logf(s));
}

// ---------------------------------------------------------------------------
__global__ __launch_bounds__(256) void finalize_kernel(
    const float* __restrict__ velpart, const float* __restrict__ logppart,
    const int* __restrict__ wstart, const int* __restrict__ wend,
    void* __restrict__ out, const int* __restrict__ dflag)
{
    const int f32 = *dflag;
    __shared__ float r1[256], r2[256];
    int tid = threadIdx.x;
    float s1 = 0.f, s2 = 0.f;
    for (int r = tid; r < cB * cWIN; r += 256) {
        s1 += velpart[r];
        s2 += logppart[r];
    }
    r1[tid] = s1; r2[tid] = s2; __syncthreads();
    for (int off = 128; off > 0; off >>= 1) {
        if (tid < off) { r1[tid] += r1[tid + off]; r2[tid] += r2[tid + off]; }
        __syncthreads();
    }
    if (tid == 0) {
        float cnt = 0.f;
        for (int b = 0; b < cB; ++b)
            cnt += (float)min(max(wend[b] - wstart[b], 0), cWIN);
        cnt = fmaxf(cnt, 1.f);
        float vel = r1[0] / (cnt * (float)cD);
        float recon = -r2[0] / cnt;
        float loss = vel + cRECON_W * recon;
        if (f32) ((float*)out)[0] = loss;
        else     ((bf16*)out)[0] = __float2bfloat16(loss);
    }
}

// ===========================================================================
extern "C" void kernel_launch(void* const* d_in, const int* in_sizes, int n_in,
                              void* d_out, int out_size, void* d_ws, size_t ws_size,
                              hipStream_t stream) {
    const int*  token_ids    = (const int*)d_in[0];
    const int*  motif_ids    = (const int*)d_in[1];
    const int*  motif_len    = (const int*)d_in[2];
    const int*  window_start = (const int*)d_in[3];
    const int*  window_end   = (const int*)d_in[4];
    const void* t_arr        = d_in[5];
    const void* x0           = d_in[6];
    const void* embed_table  = d_in[7];
    const void* decode_W     = d_in[8];
    const void* decode_b     = d_in[9];
    const void* adapter_W    = d_in[10];
    const void* adapter_b    = d_in[11];
    const void* time_proj_W  = d_in[12];
    const void* time_proj_b  = d_in[13];
    const void* cond_proj_W  = d_in[14];
    const void* cond_proj_b  = d_in[15];
    const void* qkv_W        = d_in[16];
    const void* qkv_b        = d_in[17];
    const void* attn_out_W   = d_in[18];
    const void* attn_out_b   = d_in[19];
    const void* ff1_W        = d_in[20];
    const void* ff1_b        = d_in[21];
    const void* ff2_W        = d_in[22];
    const void* ff2_b        = d_in[23];
    const void* ln1_g        = d_in[24];
    const void* ln1_b        = d_in[25];
    const void* ln2_g        = d_in[26];
    const void* ln2_b        = d_in[27];
    const void* out_W        = d_in[28];
    const void* out_b        = d_in[29];

    float* w = (float*)d_ws;
    const size_t SZ_X   = (size_t)cB * cS * cD;       // 2064*512
    const size_t SZ_BA  = (size_t)cB * cS * cFF;      // 2064*2048
    const size_t SZ_ROW = (size_t)cB * cWIN * cD;     // 2048*512
    float* x     = w;
    float* bufA  = x + SZ_X;
    float* bufB  = bufA + SZ_BA;
    float* bufC  = bufB + SZ_X;
    float* x1b   = bufC + SZ_X;
    float* xtb   = x1b + SZ_ROW;
    float* pvb   = xtb + SZ_ROW;
    float* h2b   = pvb + SZ_ROW;                      // region reused for bf16 bufs
    float* feat  = h2b + SZ_ROW;                      // (legacy slot, unused)
    float* tfb   = feat + (size_t)cB * 4 * cD;
    float* cond  = tfb + (size_t)cB * cD;
    float* temb  = cond + (size_t)cB * cD;
    float* velpart = temb + (size_t)cB * cD;
    float* logppart = velpart + (size_t)cB * cWIN;
    int*   dflag = (int*)(logppart + (size_t)cB * cWIN);
    int*   labels = (int*)(dflag + 16);               // DEDICATED slot (never aliased)
    float* wsend = (float*)(labels + (size_t)cB * cWIN);  // end of base layout
    unsigned short* wbf = (unsigned short*)wsend;     // [cV*cD] bf16 W copy

    const size_t need_bytes = ((char*)wsend - (char*)d_ws)
                            + (size_t)cV * cD * sizeof(unsigned short) + 256;
    const bool fast_decode = ws_size >= need_bytes;

    const int Wrows = cB * cWIN;                      // 2048
    const int Mrows = cB * cS;                        // 2064

    // bf16 buffers carved from existing f32 regions (all uses time-disjoint):
    unsigned short* xbf    = (unsigned short*)h2b;              // [2064][512]
    unsigned short* featbf = xbf + (size_t)Mrows * cD;          // [16][2048]
    unsigned short* tfbbf  = featbf + (size_t)cB * 4 * cD;      // [16][512]
    unsigned short* qkvbf  = (unsigned short*)bufA;             // [2064][1536]
    unsigned short* ff1bf  = (unsigned short*)bufA;             // [2064][2048]
    unsigned short* ctxbf  = (unsigned short*)bufB;             // [2064][512]
    unsigned short* px1bf  = (unsigned short*)(bufA + (size_t)3 * 1024 * 1024);
    unsigned short* hbf    = (unsigned short*)bufC;             // [2048][512]

    float* pm  = bufA;                                // decode partials in bufA
    float* ps  = pm + (size_t)Wrows * cNVT;
    float* lab = ps + (size_t)Wrows * cNVT;
    float* poolspart = bufC;                          // pools partials in bufC

    auto gemm = [&](const unsigned short* A, const void* W, size_t wOff,
                    const void* bias, size_t bOff, float* Cf, unsigned short* Cbf,
                    int M_, int N_, int K_, int relu, int obf, int amap) {
        dim3 grid(N_ / 64, (M_ + 63) / 64);
        gemm_bf<<<grid, 512, 0, stream>>>(A, W, wOff, bias, bOff, Cf, Cbf,
                                          M_, N_, K_, relu, obf, amap, dflag);
    };

    detect_kernel<<<1, 256, 0, stream>>>(x0, dflag);
    if (fast_decode)
        cvt_w_kernel<<<2048, 256, 0, stream>>>(decode_W, wbf, dflag);
    pools_part_kernel<<<dim3(16, cB), cD, 0, stream>>>(token_ids, window_start,
        window_end, embed_table, poolspart, dflag);
    pools_combine_kernel<<<cB, cD, 0, stream>>>(poolspart, motif_ids, motif_len,
        window_start, window_end, embed_table, featbf, t_arr, tfbbf,
        token_ids, labels, dflag);
    gemm(featbf, cond_proj_W, 0, cond_proj_b, 0, cond, nullptr, cB, cD, 4 * cD, 0, 0, 0);
    gemm(tfbbf, time_proj_W, 0, time_proj_b, 0, temb, nullptr, cB, cD, cD, 0, 0, 0);
    build_x_kernel<<<Mrows, cD, 0, stream>>>(token_ids, window_start, window_end,
        t_arr, x0, embed_table, cond, temb, x, xbf, x1b, xtb, dflag);

    for (int i = 0; i < cNL; ++i) {
        gemm(xbf, qkv_W, (size_t)i * 3 * cD * cD, qkv_b, (size_t)i * 3 * cD,
             nullptr, qkvbf, Mrows, 3 * cD, cD, 0, 1, 0);
        attn_mfma_kernel<<<dim3(cH, cB, 3), 256, 0, stream>>>(qkvbf, ctxbf);
        gemm(ctxbf, attn_out_W, (size_t)i * cD * cD, attn_out_b, (size_t)i * cD,
             bufC, nullptr, Mrows, cD, cD, 0, 0, 0);
        resid_ln_kernel<<<Mrows, 256, 0, stream>>>(x, bufC, ln1_g, ln1_b,
             (size_t)i * cD, xbf, dflag);
        gemm(xbf, ff1_W, (size_t)i * cFF * cD, ff1_b, (size_t)i * cFF,
             nullptr, ff1bf, Mrows, cFF, cD, 1, 1, 0);
        gemm(ff1bf, ff2_W, (size_t)i * cD * cFF, ff2_b, (size_t)i * cD,
             bufC, nullptr, Mrows, cD, cFF, 0, 0, 0);
        resid_ln_kernel<<<Mrows, 256, 0, stream>>>(x, bufC, ln2_g, ln2_b,
             (size_t)i * cD, xbf, dflag);
    }

    // out_W GEMM reads xbf directly with row remap (copy_xs fused away)
    gemm(xbf, out_W, 0, out_b, 0, pvb, nullptr, Wrows, cD, cD, 0, 0, 1);
    predvel_kernel<<<Wrows, 512, 0, stream>>>(xtb, pvb, x1b, x0, t_arr,
        window_start, window_end, px1bf, velpart, dflag);
    gemm(px1bf, adapter_W, 0, adapter_b, 0, nullptr, hbf, Wrows, cD, cD, 0, 1, 0);

    if (fast_decode) {
        decode_mfma2_kernel<<<4096, 256, 0, stream>>>(
            hbf, wbf, decode_W, decode_b, labels, pm, ps, lab, dflag);
    } else {
        decode_mfma_kernel<<<dim3(cNVT, Wrows / 128), 256, 0, stream>>>(
            hbf, decode_W, decode_b, labels, pm, ps, lab, dflag);
    }
    lse_reduce_kernel<<<Wrows, 64, 0, stream>>>(pm, ps, lab, labels, logppart);

    finalize_kernel<<<1, 256, 0, stream>>>(velpart, logppart,
        window_start, window_end, d_out, dflag);
}

// Round 11
// 802.789 us; speedup vs baseline: 1.0266x; 1.0266x over previous
//
#include <hip/hip_runtime.h>
#include <hip/hip_bf16.h>
#include <math.h>

typedef __hip_bfloat16 bf16;

// Problem constants
constexpr int cB = 16, cL = 2048, cWIN = 128, cD = 512, cH = 8, cFF = 2048;
constexpr int cNL = 3, cV = 32000, cM = 32;
constexpr int cHD = cD / cH;     // 64
constexpr int cS = cWIN + 1;     // 129
constexpr float cEPS = 1e-5f;
constexpr float cRECON_W = 0.1f;
constexpr int cNVT = cV / 128;   // 250 vocab tiles

__device__ __forceinline__ float b2f(bf16 x) { return __bfloat162float(x); }

// dtype-agnostic load with ELEMENT offset: f32 flag selects interpretation.
__device__ __forceinline__ float ldx(const void* p, size_t i, int f32) {
    return f32 ? ((const float*)p)[i]
               : __bfloat162float(((const bf16*)p)[i]);
}

// f32 -> bf16 bits, round-to-nearest-even
__device__ __forceinline__ unsigned int f2bf(float f) {
    union { float f; unsigned int u; } v; v.f = f;
    unsigned int u = v.u + 0x7FFFu + ((v.u >> 16) & 1u);
    return u >> 16;
}

// async global->LDS 16B per lane (dest = wave-uniform base + lane*16)
__device__ __forceinline__ void glds16(const unsigned short* g, unsigned short* l) {
    __builtin_amdgcn_global_load_lds(
        (const __attribute__((address_space(1))) void*)g,
        (__attribute__((address_space(3))) void*)l, 16, 0, 0);
}

// MFMA fragment types
typedef short bf16x8 __attribute__((ext_vector_type(8)));
typedef float f32x4  __attribute__((ext_vector_type(4)));

// ---------------------------------------------------------------------------
__global__ void detect_kernel(const void* __restrict__ x0raw, int* __restrict__ flag)
{
    const unsigned short* h = (const unsigned short*)x0raw;
    int tid = threadIdx.x;
    int cnt = 0;
    for (int j = tid; j < 8192; j += 256) {
        unsigned short u = h[2 * j];
        int e = (u >> 7) & 0xFF;
        if (e >= 134) cnt++;
    }
    __shared__ int red[256];
    red[tid] = cnt; __syncthreads();
    for (int off = 128; off > 0; off >>= 1) {
        if (tid < off) red[tid] += red[tid + off];
        __syncthreads();
    }
    if (tid == 0) *flag = (red[0] > 400) ? 1 : 0;
}

// ---------------------------------------------------------------------------
// 16 chunks (256 blocks) for occupancy; 128 tokens each.
__global__ __launch_bounds__(512) void pools_part_kernel(
    const int* __restrict__ tok, const int* __restrict__ wstart,
    const int* __restrict__ wend, const void* __restrict__ emb,
    float* __restrict__ part, const int* __restrict__ dflag)
{
    const int f32 = *dflag;
    int chunk = blockIdx.x;          // 0..15
    int b = blockIdx.y;              // 0..15
    int d = threadIdx.x;             // 0..511
    int ws_ = wstart[b], we_ = wend[b];
    float sl = 0.f, sr = 0.f, sg = 0.f;
    int l0 = chunk * 128;
    for (int l = l0; l < l0 + 128; ++l) {
        int t = tok[b * cL + l];
        float h = ldx(emb, (size_t)t * cD + d, f32);
        sg += h;
        if (l < ws_) sl += h;
        if (l >= we_) sr += h;
    }
    size_t base = ((size_t)(b * 16 + chunk)) * 3 * cD;
    part[base + d]            = sl;
    part[base + cD + d]       = sr;
    part[base + 2 * cD + d]   = sg;
}

// combine partials + FUSED time-embedding + FUSED labels (labels live in a
// DEDICATED workspace slot never aliased by GEMM buffers).
__global__ __launch_bounds__(512) void pools_combine_kernel(
    const float* __restrict__ part, const int* __restrict__ mids,
    const int* __restrict__ mlen, const int* __restrict__ wstart,
    const int* __restrict__ wend, const void* __restrict__ emb,
    unsigned short* __restrict__ featb, const void* __restrict__ t_arr,
    unsigned short* __restrict__ tfbb, const int* __restrict__ tok,
    int* __restrict__ labels, const int* __restrict__ dflag)
{
    const int f32 = *dflag;
    int b = blockIdx.x;
    int d = threadIdx.x;
    int ws_ = wstart[b], we_ = wend[b];
    float sl = 0.f, sr = 0.f, sg = 0.f;
    for (int c = 0; c < 16; ++c) {
        size_t base = ((size_t)(b * 16 + c)) * 3 * cD;
        sl += part[base + d];
        sr += part[base + cD + d];
        sg += part[base + 2 * cD + d];
    }
    int ml = mlen[b];
    float sm = 0.f;
    for (int j = 0; j < cM; ++j) {
        if (j < ml) sm += ldx(emb, (size_t)mids[b * cM + j] * cD + d, f32);
    }
    unsigned short* fr = featb + (size_t)b * (4 * cD);
    fr[d]            = (unsigned short)f2bf(sm / fmaxf((float)ml, 1.f));
    fr[cD + d]       = (unsigned short)f2bf(sl / fmaxf((float)ws_, 1.f));
    fr[2 * cD + d]   = (unsigned short)f2bf(sr / fmaxf((float)(cL - we_), 1.f));
    fr[3 * cD + d]   = (unsigned short)f2bf(sg / (float)cL);

    // fused tf: time-frequency embedding row b
    {
        float t = ldx(t_arr, b, f32);
        const int half = cD / 2;
        float v;
        if (d < half) {
            float frq = expf(-logf(10000.f) * (float)d / (float)(half - 1));
            v = sinf(t * frq);
        } else {
            float frq = expf(-logf(10000.f) * (float)(d - half) / (float)(half - 1));
            v = cosf(t * frq);
        }
        tfbb[(size_t)b * cD + d] = (unsigned short)f2bf(v);
    }

    // fused labels: rows b*128 .. b*128+127 (dedicated buffer)
    if (d < cWIN) {
        int actual = min(max(we_ - ws_, 0), cWIN);
        labels[b * cWIN + d] =
            (d < actual) ? tok[b * cL + min(ws_ + d, cL - 1)] : -1;
    }
}

// ---------------------------------------------------------------------------
__global__ __launch_bounds__(512) void build_x_kernel(
    const int* __restrict__ tok, const int* __restrict__ wstart,
    const int* __restrict__ wend, const void* __restrict__ t_arr,
    const void* __restrict__ x0, const void* __restrict__ emb,
    const float* __restrict__ cond, const float* __restrict__ temb,
    float* __restrict__ x, unsigned short* __restrict__ xbf,
    float* __restrict__ x1, float* __restrict__ xt,
    const int* __restrict__ dflag)
{
    const int f32 = *dflag;
    int row = blockIdx.x;
    int b = row / cS, s = row % cS;
    int d = threadIdx.x;
    if (s == 0) {
        float cv = cond[b * cD + d];
        x[(size_t)row * cD + d] = cv;
        xbf[(size_t)row * cD + d] = (unsigned short)f2bf(cv);
        return;
    }
    int i = s - 1;
    int ws_ = wstart[b], we_ = wend[b];
    int actual = min(max(we_ - ws_, 0), cWIN);
    int idx = min(ws_ + i, cL - 1);
    float x1v = 0.f;
    if (i < actual) x1v = ldx(emb, (size_t)tok[b * cL + idx] * cD + d, f32);
    float t = ldx(t_arr, b, f32);
    float x0v = ldx(x0, ((size_t)b * cWIN + i) * cD + d, f32);
    float xtv = (1.f - t) * x0v + t * x1v;
    size_t ro = ((size_t)b * cWIN + i) * cD + d;
    x1[ro] = x1v;
    xt[ro] = xtv;
    float xv = xtv + temb[b * cD + d];
    x[(size_t)row * cD + d] = xv;
    xbf[(size_t)row * cD + d] = (unsigned short)f2bf(xv);
}

// ---------------------------------------------------------------------------
// R14 GEMM (proven 803us config): 512 threads / 8 waves per 64x64 tile.
// Each wave owns a 16x32 output sub-tile. BK=64, double-buffered LDS,
// PREFETCH-2, involutive slot-XOR on LDS write+read.
// amap=1: A rows remapped gr -> (gr>>7)*cS + 1 + (gr&127).
constexpr int GL2 = 72;   // LDS row stride in shorts (144 B)
__global__ __launch_bounds__(512) void gemm_bf(
    const unsigned short* __restrict__ Abf, const void* __restrict__ Wb,
    size_t wOff, const void* __restrict__ biasb, size_t bOff,
    float* __restrict__ Cf, unsigned short* __restrict__ Cbf,
    int Mdim, int Ndim, int Kdim, int relu, int obf, int amap,
    const int* __restrict__ dflag)
{
    const int f32 = *dflag;
    const float* Wf = (const float*)Wb + wOff;
    const unsigned short* Wh = (const unsigned short*)Wb + wOff;
    __shared__ unsigned short As[2][64 * GL2];
    __shared__ unsigned short Bs[2][64 * GL2];
    const int tid = threadIdx.x;
    const int lane = tid & 63;
    const int wid = tid >> 6;          // 0..7
    const int wm = wid >> 1;           // 0..3: 16-row band
    const int wn = wid & 1;            // 0..1: 32-col band
    const int quad = lane >> 4, lm = lane & 15;
    const int m0 = blockIdx.y * 64;
    const int n0 = blockIdx.x * 64;

    f32x4 acc0 = (f32x4){0.f, 0.f, 0.f, 0.f};
    f32x4 acc1 = (f32x4){0.f, 0.f, 0.f, 0.f};

    const int srow = tid >> 3;                       // 0..63
    const int sc8  = (tid & 7) * 8;                  // global short offset
    const int ssw  = ((tid & 7) ^ ((tid >> 3) & 7)) * 8;  // swizzled LDS slot
    const int lmm  = lm & 7;                         // read-side row&7

    auto loadA = [&](int k0, uint4& r) {
        int r0 = m0 + srow;
        uint4 v = {0u, 0u, 0u, 0u};
        if (r0 < Mdim) {
            size_t ar = amap ? ((size_t)(r0 >> 7) * cS + 1 + (r0 & 127))
                             : (size_t)r0;
            v = *(const uint4*)(Abf + ar * Kdim + k0 + sc8);
        }
        r = v;
    };
    auto loadB = [&](int k0, uint4& r) {
        size_t g = (size_t)(n0 + srow) * Kdim + k0 + sc8;
        if (f32) {
            float4 v0 = *(const float4*)(Wf + g);
            float4 v1 = *(const float4*)(Wf + g + 4);
            r = make_uint4(
                f2bf(v0.x) | (f2bf(v0.y) << 16), f2bf(v0.z) | (f2bf(v0.w) << 16),
                f2bf(v1.x) | (f2bf(v1.y) << 16), f2bf(v1.z) | (f2bf(v1.w) << 16));
        } else {
            r = *(const uint4*)(Wh + g);
        }
    };
    auto stores = [&](int buf, const uint4& ra, const uint4& rb) {
        *(uint4*)(&As[buf][srow * GL2 + ssw]) = ra;
        *(uint4*)(&Bs[buf][srow * GL2 + ssw]) = rb;
    };
    auto compute = [&](int buf) {
        #pragma unroll
        for (int kk = 0; kk < 2; ++kk) {
            const int sl = ((kk * 4 + quad) ^ lmm) * 8;
            bf16x8 a0 = *(const bf16x8*)(&As[buf][(wm * 16 + lm) * GL2 + sl]);
            bf16x8 b0 = *(const bf16x8*)(&Bs[buf][(wn * 32 + lm) * GL2 + sl]);
            bf16x8 b1 = *(const bf16x8*)(&Bs[buf][(wn * 32 + 16 + lm) * GL2 + sl]);
            acc0 = __builtin_amdgcn_mfma_f32_16x16x32_bf16(a0, b0, acc0, 0, 0, 0);
            acc1 = __builtin_amdgcn_mfma_f32_16x16x32_bf16(a0, b1, acc1, 0, 0, 0);
        }
    };

    uint4 raA, rbA, raB, rbB;
    loadA(0, raA);  loadB(0, rbA);
    loadA(64, raB); loadB(64, rbB);
    const int nk = Kdim >> 6;          // even for all call sites
    for (int t = 0; t < nk; t += 2) {
        stores(0, raA, rbA);
        __syncthreads();
        if (t + 2 < nk) { loadA((t + 2) * 64, raA); loadB((t + 2) * 64, rbA); }
        compute(0);
        stores(1, raB, rbB);
        __syncthreads();
        if (t + 3 < nk) { loadA((t + 3) * 64, raB); loadB((t + 3) * 64, rbB); }
        compute(1);
    }

    #pragma unroll
    for (int in = 0; in < 2; ++in) {
        int gc = n0 + wn * 32 + in * 16 + lm;
        float bv = ldx(biasb, bOff + gc, f32);
        const f32x4& a = in ? acc1 : acc0;
        #pragma unroll
        for (int r = 0; r < 4; ++r) {
            int gr = m0 + wm * 16 + quad * 4 + r;
            if (gr < Mdim) {
                float v = a[r] + bv;
                if (relu) v = fmaxf(v, 0.f);
                if (obf) Cbf[(size_t)gr * Ndim + gc] = (unsigned short)f2bf(v);
                else     Cf[(size_t)gr * Ndim + gc] = v;
            }
        }
    }
}

// ---------------------------------------------------------------------------
// MFMA flash-style attention, bf16 I/O, z-split grid: grid (H, B, 3);
// wave wid<3 of block z owns query tile t = z*3 + wid (9 tiles total).
__global__ __launch_bounds__(256) void attn_mfma_kernel(
    const unsigned short* __restrict__ qkv, unsigned short* __restrict__ ctx)
{
    constexpr int SP = 160;        // padded S (10 * 16)
    constexpr int KP = 72;         // Ks row stride in shorts
    constexpr int VP = 168;        // Vt / P row stride in shorts
    const int h = blockIdx.x, b = blockIdx.y, z = blockIdx.z;
    const int tid = threadIdx.x;
    const int lane = tid & 63;
    const int wid = tid >> 6;
    const int quad = lane >> 4, lm = lane & 15;

    __shared__ unsigned short Ks[SP * KP];       // [key][64]
    __shared__ unsigned short Vt[64 * VP];       // [d][key]
    __shared__ unsigned short Pl[4 * 16 * VP];   // per-wave [qrow][key]

    const unsigned short* base = qkv + (size_t)b * cS * (3 * cD) + h * cHD;

    // Stage K row-major (uint4 = 8 bf16 per chunk)
    for (int c = tid; c < SP * 8; c += 256) {
        int row = c >> 3, g = c & 7;
        uint4 v = {0u, 0u, 0u, 0u};
        if (row < cS)
            v = *(const uint4*)(base + (size_t)row * (3 * cD) + cD + g * 8);
        *(uint4*)(Ks + row * KP + g * 8) = v;
    }
    // Stage V transposed (uint2 = 4 bf16, scattered per-d rows)
    for (int c = tid; c < SP * 16; c += 256) {
        int key = c >> 4, d4 = c & 15;
        uint2 v = {0u, 0u};
        if (key < cS)
            v = *(const uint2*)(base + (size_t)key * (3 * cD) + 2 * cD + d4 * 4);
        Vt[(d4 * 4 + 0) * VP + key] = (unsigned short)(v.x & 0xFFFFu);
        Vt[(d4 * 4 + 1) * VP + key] = (unsigned short)(v.x >> 16);
        Vt[(d4 * 4 + 2) * VP + key] = (unsigned short)(v.y & 0xFFFFu);
        Vt[(d4 * 4 + 3) * VP + key] = (unsigned short)(v.y >> 16);
    }
    __syncthreads();

    unsigned short* Pw = Pl + wid * (16 * VP);
    const int t = z * 3 + wid;        // 9 tiles, wid==3 idles after staging

    if (wid < 3 && t < 9) {
        int qs = t * 16 + lm;
        bf16x8 aq[2];
        #pragma unroll
        for (int j = 0; j < 8; ++j) { aq[0][j] = 0; aq[1][j] = 0; }
        if (qs < cS) {
            const unsigned short* qrow = base + (size_t)qs * (3 * cD);
            aq[0] = *(const bf16x8*)(qrow + quad * 8);
            aq[1] = *(const bf16x8*)(qrow + 32 + quad * 8);
        }

        // scores: sc[n][r] = S[q = t*16 + quad*4 + r][key = n*16 + lm]
        f32x4 sc[10];
        #pragma unroll
        for (int n = 0; n < 10; ++n) {
            sc[n] = (f32x4){0.f, 0.f, 0.f, 0.f};
            bf16x8 bk0 = *(const bf16x8*)(Ks + (n * 16 + lm) * KP + quad * 8);
            sc[n] = __builtin_amdgcn_mfma_f32_16x16x32_bf16(aq[0], bk0, sc[n], 0, 0, 0);
            bf16x8 bk1 = *(const bf16x8*)(Ks + (n * 16 + lm) * KP + 32 + quad * 8);
            sc[n] = __builtin_amdgcn_mfma_f32_16x16x32_bf16(aq[1], bk1, sc[n], 0, 0, 0);
        }

        // softmax per accumulator row; key-dim lives across the 16 lm lanes
        #pragma unroll
        for (int r = 0; r < 4; ++r) {
            float mx = -3.0e38f;
            #pragma unroll
            for (int n = 0; n < 10; ++n) {
                float v = sc[n][r] * 0.125f;
                mx = fmaxf(mx, ((n * 16 + lm) < cS) ? v : -3.0e38f);
            }
            #pragma unroll
            for (int msk = 1; msk < 16; msk <<= 1)
                mx = fmaxf(mx, __shfl_xor(mx, msk));
            float p[10];
            float sum = 0.f;
            #pragma unroll
            for (int n = 0; n < 10; ++n) {
                float e = ((n * 16 + lm) < cS) ? expf(sc[n][r] * 0.125f - mx) : 0.f;
                p[n] = e; sum += e;
            }
            #pragma unroll
            for (int msk = 1; msk < 16; msk <<= 1)
                sum += __shfl_xor(sum, msk);
            float inv = 1.f / sum;
            unsigned short* pr = Pw + (quad * 4 + r) * VP + lm;
            #pragma unroll
            for (int n = 0; n < 10; ++n)
                pr[n * 16] = (unsigned short)f2bf(p[n] * inv);
        }

        // per-wave LDS visibility for P; sched_barrier per guide rule 18
        asm volatile("s_waitcnt lgkmcnt(0)" ::: "memory");
        __builtin_amdgcn_sched_barrier(0);

        // PV: O[16][64] = P[16][160] @ V[160][64]
        f32x4 o[4];
        #pragma unroll
        for (int j = 0; j < 4; ++j) o[j] = (f32x4){0.f, 0.f, 0.f, 0.f};
        #pragma unroll
        for (int ks = 0; ks < 5; ++ks) {
            bf16x8 ap = *(const bf16x8*)(Pw + lm * VP + ks * 32 + quad * 8);
            #pragma unroll
            for (int j = 0; j < 4; ++j) {
                bf16x8 bv = *(const bf16x8*)(Vt + (j * 16 + lm) * VP + ks * 32 + quad * 8);
                o[j] = __builtin_amdgcn_mfma_f32_16x16x32_bf16(ap, bv, o[j], 0, 0, 0);
            }
        }

        #pragma unroll
        for (int r = 0; r < 4; ++r) {
            int s_ = t * 16 + quad * 4 + r;
            if (s_ < cS) {
                unsigned short* orow = ctx + ((size_t)(b * cS + s_)) * cD + h * cHD;
                #pragma unroll
                for (int j = 0; j < 4; ++j)
                    orow[j * 16 + lm] = (unsigned short)f2bf(o[j][r]);
            }
        }
    }
}

// ---------------------------------------------------------------------------
__global__ __launch_bounds__(256) void resid_ln_kernel(
    float* __restrict__ x, const float* __restrict__ h,
    const void* __restrict__ g, const void* __restrict__ bta, size_t off,
    unsigned short* __restrict__ xbf, const int* __restrict__ dflag)
{
    const int f32 = *dflag;
    int row = blockIdx.x;
    int tid = threadIdx.x;
    __shared__ float red[256];
    float v[2];
    float s = 0.f;
    #pragma unroll
    for (int j = 0; j < 2; ++j) {
        int d = tid + j * 256;
        v[j] = x[(size_t)row * cD + d] + h[(size_t)row * cD + d];
        s += v[j];
    }
    red[tid] = s; __syncthreads();
    for (int o = 128; o > 0; o >>= 1) {
        if (tid < o) red[tid] += red[tid + o];
        __syncthreads();
    }
    float mean = red[0] / (float)cD;
    __syncthreads();
    float vs = 0.f;
    #pragma unroll
    for (int j = 0; j < 2; ++j) { float dd = v[j] - mean; vs += dd * dd; }
    red[tid] = vs; __syncthreads();
    for (int o = 128; o > 0; o >>= 1) {
        if (tid < o) red[tid] += red[tid + o];
        __syncthreads();
    }
    float rs = rsqrtf(red[0] / (float)cD + cEPS);
    #pragma unroll
    for (int j = 0; j < 2; ++j) {
        int d = tid + j * 256;
        float ov = (v[j] - mean) * rs * ldx(g, off + d, f32) + ldx(bta, off + d, f32);
        x[(size_t)row * cD + d] = ov;
        xbf[(size_t)row * cD + d] = (unsigned short)f2bf(ov);
    }
}

// ---------------------------------------------------------------------------
// Fused predx1 + vel: one pass over pv; writes bf16 pred_x1 and the
// per-row velocity partial.
__global__ __launch_bounds__(512) void predvel_kernel(
    const float* __restrict__ xt, const float* __restrict__ pv,
    const float* __restrict__ x1, const void* __restrict__ x0,
    const void* __restrict__ t_arr, const int* __restrict__ wstart,
    const int* __restrict__ wend, unsigned short* __restrict__ px1,
    float* __restrict__ velpart, const int* __restrict__ dflag)
{
    const int f32 = *dflag;
    int row = blockIdx.x;
    int b = row >> 7, i = row & 127;
    int d = threadIdx.x;
    float t = ldx(t_arr, b, f32);
    size_t o = (size_t)row * cD + d;
    float pvv = pv[o];
    px1[o] = (unsigned short)f2bf(xt[o] + (1.f - t) * pvv);
    int actual = min(max(wend[b] - wstart[b], 0), cWIN);
    float s = 0.f;
    if (i < actual) {
        float tv = x1[o] - ldx(x0, o, f32);
        float diff = pvv - tv;
        s = diff * diff;
    }
    __shared__ float red[512];
    red[d] = s; __syncthreads();
    for (int off = 256; off > 0; off >>= 1) {
        if (d < off) red[d] += red[d + off];
        __syncthreads();
    }
    if (d == 0) velpart[row] = red[0];
}

// ---------------------------------------------------------------------------
// pre-convert decode_W -> bf16 (only needed when input is f32)
__global__ __launch_bounds__(256) void cvt_w_kernel(
    const void* __restrict__ Wsrc, unsigned short* __restrict__ dst,
    const int* __restrict__ dflag)
{
    if (!*dflag) return;   // bf16 input: decode reads source directly
    const float4* src = (const float4*)Wsrc;
    size_t n4 = (size_t)cV * cD / 4;
    for (size_t i = (size_t)blockIdx.x * 256 + threadIdx.x; i < n4;
         i += (size_t)gridDim.x * 256) {
        float4 v = src[i];
        unsigned int p0 = f2bf(v.x) | (f2bf(v.y) << 16);
        unsigned int p1 = f2bf(v.z) | (f2bf(v.w) << 16);
        ((uint2*)dst)[i] = make_uint2(p0, p1);
    }
}

// ---------------------------------------------------------------------------
// FAST decode (proven 124 us): global_load_lds width-16 staging into
// LINEAR [128][32] LDS with an involutive slot swizzle on the per-lane GLOBAL
// source and the ds_read side (rule 21). Staging LDS unioned with the softmax
// epilogue buffers (17.4 KB).
__global__ __launch_bounds__(256) void decode_mfma2_kernel(
    const unsigned short* __restrict__ hbf, const unsigned short* __restrict__ wbf,
    const void* __restrict__ dW, const void* __restrict__ db,
    const int* __restrict__ labels,
    float* __restrict__ pm, float* __restrict__ ps, float* __restrict__ lab,
    const int* __restrict__ dflag)
{
    const int f32 = *dflag;
    const unsigned short* Wsrc = f32 ? wbf : (const unsigned short*)dW;
    const int bid = blockIdx.x;
    const int xcd = bid & 7;
    const int local = bid >> 3;            // 0..511
    const int nt = xcd * 32 + (local >> 4);
    const int mt = local & 15;
    if (nt >= cNVT) return;                // uniform exit, no barriers crossed
    const int m0 = mt * 128, n0 = nt * 128;

    __shared__ __align__(16) char smem[17408];   // max(2*8192 staging, red+mrow)
    unsigned short* As = (unsigned short*)smem;  // [128][32] linear
    unsigned short* Bs = As + 4096;              // [128][32] linear

    const int tid = threadIdx.x;
    const int lane = tid & 63;
    const int wid = tid >> 6;
    const int wm = wid >> 1, wn = wid & 1;
    const int quad = lane >> 4, lm = lane & 15;

    // staging geometry: each glds16 covers 16 rows (64 lanes x 16 B = 1 KB)
    const int grow  = lane >> 2;                       // row within chunk
    const int gslot = (lane & 3) ^ ((lane >> 3) & 3);  // swizzled global slot
    const int rslot = (quad ^ ((lm >> 1) & 3)) * 8;    // read-side slot (shorts)

    // per-wave global bases (rows wid*32 .. wid*32+31 over two chunks)
    const unsigned short* gA = hbf  + (size_t)(m0 + wid * 32 + grow) * cD + gslot * 8;
    const unsigned short* gB = Wsrc + (size_t)(n0 + wid * 32 + grow) * cD + gslot * 8;

    f32x4 acc[4][4];
    #pragma unroll
    for (int i = 0; i < 4; ++i)
        #pragma unroll
        for (int j = 0; j < 4; ++j)
            acc[i][j] = (f32x4){0.f, 0.f, 0.f, 0.f};

    for (int k0 = 0; k0 < cD; k0 += 32) {
        #pragma unroll
        for (int c = 0; c < 2; ++c) {
            glds16(gA + (size_t)c * 16 * cD + k0, As + (wid * 2 + c) * 512);
            glds16(gB + (size_t)c * 16 * cD + k0, Bs + (wid * 2 + c) * 512);
        }
        __syncthreads();     // drains vmcnt (compiler) -> tiles visible
        bf16x8 af[4], bfr[4];
        #pragma unroll
        for (int im = 0; im < 4; ++im)
            af[im] = *(const bf16x8*)(As + (wm * 64 + im * 16 + lm) * 32 + rslot);
        #pragma unroll
        for (int in = 0; in < 4; ++in)
            bfr[in] = *(const bf16x8*)(Bs + (wn * 64 + in * 16 + lm) * 32 + rslot);
        #pragma unroll
        for (int im = 0; im < 4; ++im)
            #pragma unroll
            for (int in = 0; in < 4; ++in)
                acc[im][in] = __builtin_amdgcn_mfma_f32_16x16x32_bf16(
                    af[im], bfr[in], acc[im][in], 0, 0, 0);
        __syncthreads();
    }

    float bv[4];
    #pragma unroll
    for (int in = 0; in < 4; ++in)
        bv[in] = ldx(db, n0 + wn * 64 + in * 16 + lm, f32);
    #pragma unroll
    for (int im = 0; im < 4; ++im)
        #pragma unroll
        for (int in = 0; in < 4; ++in)
            #pragma unroll
            for (int r = 0; r < 4; ++r)
                acc[im][in][r] += bv[in];

    #pragma unroll
    for (int im = 0; im < 4; ++im) {
        #pragma unroll
        for (int r = 0; r < 4; ++r) {
            int gr = m0 + wm * 64 + im * 16 + quad * 4 + r;
            int lb = labels[gr];
            #pragma unroll
            for (int in = 0; in < 4; ++in) {
                int col = n0 + wn * 64 + in * 16 + lm;
                if (lb == col) lab[gr] = acc[im][in][r];
            }
        }
    }

    // epilogue buffers alias the (now dead) staging LDS; the k-loop's trailing
    // barrier guarantees all fragment reads completed before these writes.
    float (*red)[33] = (float(*)[33])smem;               // [128][33]
    float* mrow = (float*)(smem + 16896);                // [128]
    #pragma unroll
    for (int im = 0; im < 4; ++im) {
        #pragma unroll
        for (int r = 0; r < 4; ++r) {
            int rl = wm * 64 + im * 16 + quad * 4 + r;
            float mx = acc[im][0][r];
            #pragma unroll
            for (int in = 1; in < 4; ++in) mx = fmaxf(mx, acc[im][in][r]);
            red[rl][wn * 16 + lm] = mx;
        }
    }
    __syncthreads();
    if (tid < 128) {
        float mx = red[tid][0];
        #pragma unroll
        for (int t = 1; t < 32; ++t) mx = fmaxf(mx, red[tid][t]);
        mrow[tid] = mx;
    }
    __syncthreads();
    #pragma unroll
    for (int im = 0; im < 4; ++im) {
        #pragma unroll
        for (int r = 0; r < 4; ++r) {
            int rl = wm * 64 + im * 16 + quad * 4 + r;
            float m_ = mrow[rl];
            float s = 0.f;
            #pragma unroll
            for (int in = 0; in < 4; ++in) s += expf(acc[im][in][r] - m_);
            red[rl][wn * 16 + lm] = s;
        }
    }
    __syncthreads();
    if (tid < 128) {
        float s = red[tid][0];
        #pragma unroll
        for (int t = 1; t < 32; ++t) s += red[tid][t];
        int gr = m0 + tid;
        pm[(size_t)gr * cNVT + nt] = mrow[tid];
        ps[(size_t)gr * cNVT + nt] = s;
    }
}

// ---------------------------------------------------------------------------
// FALLBACK decode: bf16 A (hbf), in-kernel W conversion, (nt, mt) grid.
constexpr int GLDS = 40;
__global__ __launch_bounds__(256) void decode_mfma_kernel(
    const unsigned short* __restrict__ hbf, const void* __restrict__ dW,
    const void* __restrict__ db, const int* __restrict__ labels,
    float* __restrict__ pm, float* __restrict__ ps, float* __restrict__ lab,
    const int* __restrict__ dflag)
{
    const int f32 = *dflag;
    const float* Wf = (const float*)dW;
    const unsigned short* Wh = (const unsigned short*)dW;
    __shared__ unsigned short As[128 * GLDS];
    __shared__ unsigned short Bs[128 * GLDS];
    const int tid = threadIdx.x;
    const int lane = tid & 63;
    const int wid = tid >> 6;
    const int wm = wid >> 1, wn = wid & 1;
    const int quad = lane >> 4, lm = lane & 15;
    const int nt = blockIdx.x;
    const int mt = blockIdx.y;
    const int m0 = mt * 128, n0 = nt * 128;

    f32x4 acc[4][4];
    #pragma unroll
    for (int i = 0; i < 4; ++i)
        #pragma unroll
        for (int j = 0; j < 4; ++j)
            acc[i][j] = (f32x4){0.f, 0.f, 0.f, 0.f};

    for (int k0 = 0; k0 < cD; k0 += 32) {
        #pragma unroll
        for (int t = 0; t < 2; ++t) {
            int idx = tid + t * 256;
            int row = idx >> 2, c = idx & 3;
            uint4 v = *(const uint4*)(hbf + (size_t)(m0 + row) * cD + k0 + c * 8);
            *(uint4*)(As + row * GLDS + c * 8) = v;
        }
        #pragma unroll
        for (int t = 0; t < 4; ++t) {
            int chunk = tid + t * 256;
            int row = chunk >> 3;
            int kc = (chunk & 7) * 4;
            size_t gro = (size_t)(n0 + row) * cD + k0 + kc;
            if (f32) {
                float4 v = *(const float4*)(Wf + gro);
                unsigned int p0 = f2bf(v.x) | (f2bf(v.y) << 16);
                unsigned int p1 = f2bf(v.z) | (f2bf(v.w) << 16);
                *(uint2*)(Bs + row * GLDS + kc) = make_uint2(p0, p1);
            } else {
                *(uint2*)(Bs + row * GLDS + kc) = *(const uint2*)(Wh + gro);
            }
        }
        __syncthreads();
        bf16x8 af[4], bfr[4];
        #pragma unroll
        for (int im = 0; im < 4; ++im) {
            int row = wm * 64 + im * 16 + lm;
            af[im] = *(const bf16x8*)(As + row * GLDS + quad * 8);
        }
        #pragma unroll
        for (int in = 0; in < 4; ++in) {
            int row = wn * 64 + in * 16 + lm;
            bfr[in] = *(const bf16x8*)(Bs + row * GLDS + quad * 8);
        }
        #pragma unroll
        for (int im = 0; im < 4; ++im)
            #pragma unroll
            for (int in = 0; in < 4; ++in)
                acc[im][in] = __builtin_amdgcn_mfma_f32_16x16x32_bf16(
                    af[im], bfr[in], acc[im][in], 0, 0, 0);
        __syncthreads();
    }

    float bv[4];
    #pragma unroll
    for (int in = 0; in < 4; ++in)
        bv[in] = ldx(db, n0 + wn * 64 + in * 16 + lm, f32);
    #pragma unroll
    for (int im = 0; im < 4; ++im)
        #pragma unroll
        for (int in = 0; in < 4; ++in)
            #pragma unroll
            for (int r = 0; r < 4; ++r)
                acc[im][in][r] += bv[in];

    #pragma unroll
    for (int im = 0; im < 4; ++im) {
        #pragma unroll
        for (int r = 0; r < 4; ++r) {
            int gr = m0 + wm * 64 + im * 16 + quad * 4 + r;
            int lb = labels[gr];
            #pragma unroll
            for (int in = 0; in < 4; ++in) {
                int col = n0 + wn * 64 + in * 16 + lm;
                if (lb == col) lab[gr] = acc[im][in][r];
            }
        }
    }

    __shared__ float red[128][33];
    __shared__ float mrow[128];
    #pragma unroll
    for (int im = 0; im < 4; ++im) {
        #pragma unroll
        for (int r = 0; r < 4; ++r) {
            int rl = wm * 64 + im * 16 + quad * 4 + r;
            float mx = acc[im][0][r];
            #pragma unroll
            for (int in = 1; in < 4; ++in) mx = fmaxf(mx, acc[im][in][r]);
            red[rl][wn * 16 + lm] = mx;
        }
    }
    __syncthreads();
    if (tid < 128) {
        float mx = red[tid][0];
        #pragma unroll
        for (int t = 1; t < 32; ++t) mx = fmaxf(mx, red[tid][t]);
        mrow[tid] = mx;
    }
    __syncthreads();
    #pragma unroll
    for (int im = 0; im < 4; ++im) {
        #pragma unroll
        for (int r = 0; r < 4; ++r) {
            int rl = wm * 64 + im * 16 + quad * 4 + r;
            float m_ = mrow[rl];
            float s = 0.f;
            #pragma unroll
            for (int in = 0; in < 4; ++in) s += expf(acc[im][in][r] - m_);
            red[rl][wn * 16 + lm] = s;
        }
    }
    __syncthreads();
    if (tid < 128) {
        float s = red[tid][0];
        #pragma unroll
        for (int t = 1; t < 32; ++t) s += red[tid][t];
        int gr = m0 + tid;
        pm[(size_t)gr * cNVT + nt] = mrow[tid];
        ps[(size_t)gr * cNVT + nt] = s;
    }
}

// ---------------------------------------------------------------------------
__global__ __launch_bounds__(64) void lse_reduce_kernel(
    const float* __restrict__ pm, const float* __restrict__ ps,
    const float* __restrict__ lab, const int* __restrict__ labels,
    float* __restrict__ logppart)
{
    int r = blockIdx.x;
    int tid = threadIdx.x;
    if (labels[r] < 0) {
        if (tid == 0) logppart[r] = 0.f;
        return;
    }
    float m = -1e30f;
    for (int c = tid; c < cNVT; c += 64) m = fmaxf(m, pm[(size_t)r * cNVT + c]);
    for (int off = 32; off > 0; off >>= 1) m = fmaxf(m, __shfl_down(m, off));
    m = __shfl(m, 0);
    float s = 0.f;
    for (int c = tid; c < cNVT; c += 64)
        s += ps[(size_t)r * cNVT + c] * expf(pm[(size_t)r * cNVT + c] - m);
    for (int off = 32; off > 0; off >>= 1) s += __shfl_down(s, off);
    if (tid == 0) logppart[r] = lab[r] - (m + logf(s));
}

// ---------------------------------------------------------------------------
__global__ __launch_bounds__(256) void finalize_kernel(
    const float* __restrict__ velpart, const float* __restrict__ logppart,
    const int* __restrict__ wstart, const int* __restrict__ wend,
    void* __restrict__ out, const int* __restrict__ dflag)
{
    const int f32 = *dflag;
    __shared__ float r1[256], r2[256];
    int tid = threadIdx.x;
    float s1 = 0.f, s2 = 0.f;
    for (int r = tid; r < cB * cWIN; r += 256) {
        s1 += velpart[r];
        s2 += logppart[r];
    }
    r1[tid] = s1; r2[tid] = s2; __syncthreads();
    for (int off = 128; off > 0; off >>= 1) {
        if (tid < off) { r1[tid] += r1[tid + off]; r2[tid] += r2[tid + off]; }
        __syncthreads();
    }
    if (tid == 0) {
        float cnt = 0.f;
        for (int b = 0; b < cB; ++b)
            cnt += (float)min(max(wend[b] - wstart[b], 0), cWIN);
        cnt = fmaxf(cnt, 1.f);
        float vel = r1[0] / (cnt * (float)cD);
        float recon = -r2[0] / cnt;
        float loss = vel + cRECON_W * recon;
        if (f32) ((float*)out)[0] = loss;
        else     ((bf16*)out)[0] = __float2bfloat16(loss);
    }
}

// ===========================================================================
extern "C" void kernel_launch(void* const* d_in, const int* in_sizes, int n_in,
                              void* d_out, int out_size, void* d_ws, size_t ws_size,
                              hipStream_t stream) {
    const int*  token_ids    = (const int*)d_in[0];
    const int*  motif_ids    = (const int*)d_in[1];
    const int*  motif_len    = (const int*)d_in[2];
    const int*  window_start = (const int*)d_in[3];
    const int*  window_end   = (const int*)d_in[4];
    const void* t_arr        = d_in[5];
    const void* x0           = d_in[6];
    const void* embed_table  = d_in[7];
    const void* decode_W     = d_in[8];
    const void* decode_b     = d_in[9];
    const void* adapter_W    = d_in[10];
    const void* adapter_b    = d_in[11];
    const void* time_proj_W  = d_in[12];
    const void* time_proj_b  = d_in[13];
    const void* cond_proj_W  = d_in[14];
    const void* cond_proj_b  = d_in[15];
    const void* qkv_W        = d_in[16];
    const void* qkv_b        = d_in[17];
    const void* attn_out_W   = d_in[18];
    const void* attn_out_b   = d_in[19];
    const void* ff1_W        = d_in[20];
    const void* ff1_b        = d_in[21];
    const void* ff2_W        = d_in[22];
    const void* ff2_b        = d_in[23];
    const void* ln1_g        = d_in[24];
    const void* ln1_b        = d_in[25];
    const void* ln2_g        = d_in[26];
    const void* ln2_b        = d_in[27];
    const void* out_W        = d_in[28];
    const void* out_b        = d_in[29];

    float* w = (float*)d_ws;
    const size_t SZ_X   = (size_t)cB * cS * cD;       // 2064*512
    const size_t SZ_BA  = (size_t)cB * cS * cFF;      // 2064*2048
    const size_t SZ_ROW = (size_t)cB * cWIN * cD;     // 2048*512
    float* x     = w;
    float* bufA  = x + SZ_X;
    float* bufB  = bufA + SZ_BA;
    float* bufC  = bufB + SZ_X;
    float* x1b   = bufC + SZ_X;
    float* xtb   = x1b + SZ_ROW;
    float* pvb   = xtb + SZ_ROW;
    float* h2b   = pvb + SZ_ROW;                      // region reused for bf16 bufs
    float* feat  = h2b + SZ_ROW;                      // (legacy slot, unused)
    float* tfb   = feat + (size_t)cB * 4 * cD;
    float* cond  = tfb + (size_t)cB * cD;
    float* temb  = cond + (size_t)cB * cD;
    float* velpart = temb + (size_t)cB * cD;
    float* logppart = velpart + (size_t)cB * cWIN;
    int*   dflag = (int*)(logppart + (size_t)cB * cWIN);
    int*   labels = (int*)(dflag + 16);               // DEDICATED slot (never aliased)
    float* wsend = (float*)(labels + (size_t)cB * cWIN);  // end of base layout
    unsigned short* wbf = (unsigned short*)wsend;     // [cV*cD] bf16 W copy

    const size_t need_bytes = ((char*)wsend - (char*)d_ws)
                            + (size_t)cV * cD * sizeof(unsigned short) + 256;
    const bool fast_decode = ws_size >= need_bytes;

    const int Wrows = cB * cWIN;                      // 2048
    const int Mrows = cB * cS;                        // 2064

    // bf16 buffers carved from existing f32 regions (all uses time-disjoint):
    unsigned short* xbf    = (unsigned short*)h2b;              // [2064][512]
    unsigned short* featbf = xbf + (size_t)Mrows * cD;          // [16][2048]
    unsigned short* tfbbf  = featbf + (size_t)cB * 4 * cD;      // [16][512]
    unsigned short* qkvbf  = (unsigned short*)bufA;             // [2064][1536]
    unsigned short* ff1bf  = (unsigned short*)bufA;             // [2064][2048]
    unsigned short* ctxbf  = (unsigned short*)bufB;             // [2064][512]
    unsigned short* px1bf  = (unsigned short*)(bufA + (size_t)3 * 1024 * 1024);
    unsigned short* hbf    = (unsigned short*)bufC;             // [2048][512]

    float* pm  = bufA;                                // decode partials in bufA
    float* ps  = pm + (size_t)Wrows * cNVT;
    float* lab = ps + (size_t)Wrows * cNVT;
    float* poolspart = bufC;                          // pools partials in bufC

    auto gemm = [&](const unsigned short* A, const void* W, size_t wOff,
                    const void* bias, size_t bOff, float* Cf, unsigned short* Cbf,
                    int M_, int N_, int K_, int relu, int obf, int amap) {
        dim3 grid(N_ / 64, (M_ + 63) / 64);
        gemm_bf<<<grid, 512, 0, stream>>>(A, W, wOff, bias, bOff, Cf, Cbf,
                                          M_, N_, K_, relu, obf, amap, dflag);
    };

    detect_kernel<<<1, 256, 0, stream>>>(x0, dflag);
    if (fast_decode)
        cvt_w_kernel<<<2048, 256, 0, stream>>>(decode_W, wbf, dflag);
    pools_part_kernel<<<dim3(16, cB), cD, 0, stream>>>(token_ids, window_start,
        window_end, embed_table, poolspart, dflag);
    pools_combine_kernel<<<cB, cD, 0, stream>>>(poolspart, motif_ids, motif_len,
        window_start, window_end, embed_table, featbf, t_arr, tfbbf,
        token_ids, labels, dflag);
    gemm(featbf, cond_proj_W, 0, cond_proj_b, 0, cond, nullptr, cB, cD, 4 * cD, 0, 0, 0);
    gemm(tfbbf, time_proj_W, 0, time_proj_b, 0, temb, nullptr, cB, cD, cD, 0, 0, 0);
    build_x_kernel<<<Mrows, cD, 0, stream>>>(token_ids, window_start, window_end,
        t_arr, x0, embed_table, cond, temb, x, xbf, x1b, xtb, dflag);

    for (int i = 0; i < cNL; ++i) {
        gemm(xbf, qkv_W, (size_t)i * 3 * cD * cD, qkv_b, (size_t)i * 3 * cD,
             nullptr, qkvbf, Mrows, 3 * cD, cD, 0, 1, 0);
        attn_mfma_kernel<<<dim3(cH, cB, 3), 256, 0, stream>>>(qkvbf, ctxbf);
        gemm(ctxbf, attn_out_W, (size_t)i * cD * cD, attn_out_b, (size_t)i * cD,
             bufC, nullptr, Mrows, cD, cD, 0, 0, 0);
        resid_ln_kernel<<<Mrows, 256, 0, stream>>>(x, bufC, ln1_g, ln1_b,
             (size_t)i * cD, xbf, dflag);
        gemm(xbf, ff1_W, (size_t)i * cFF * cD, ff1_b, (size_t)i * cFF,
             nullptr, ff1bf, Mrows, cFF, cD, 1, 1, 0);
        gemm(ff1bf, ff2_W, (size_t)i * cD * cFF, ff2_b, (size_t)i * cD,
             bufC, nullptr, Mrows, cD, cFF, 0, 0, 0);
        resid_ln_kernel<<<Mrows, 256, 0, stream>>>(x, bufC, ln2_g, ln2_b,
             (size_t)i * cD, xbf, dflag);
    }

    // out_W GEMM reads xbf directly with row remap (copy_xs fused away)
    gemm(xbf, out_W, 0, out_b, 0, pvb, nullptr, Wrows, cD, cD, 0, 0, 1);
    predvel_kernel<<<Wrows, 512, 0, stream>>>(xtb, pvb, x1b, x0, t_arr,
        window_start, window_end, px1bf, velpart, dflag);
    gemm(px1bf, adapter_W, 0, adapter_b, 0, nullptr, hbf, Wrows, cD, cD, 0, 1, 0);

    if (fast_decode) {
        decode_mfma2_kernel<<<4096, 256, 0, stream>>>(
            hbf, wbf, decode_W, decode_b, labels, pm, ps, lab, dflag);
    } else {
        decode_mfma_kernel<<<dim3(cNVT, Wrows / 128), 256, 0, stream>>>(
            hbf, decode_W, decode_b, labels, pm, ps, lab, dflag);
    }
    lse_reduce_kernel<<<Wrows, 64, 0, stream>>>(pm, ps, lab, labels, logppart);

    finalize_kernel<<<1, 256, 0, stream>>>(velpart, logppart,
        window_start, window_end, d_out, dflag);
}